// Round 8
// baseline (193.325 us; speedup 1.0000x reference)
//
#include <hip/hip_runtime.h>
#include <hip/hip_fp16.h>
#include <math.h>

#define NPTS 131072
#define KCOMP 256
#define DIM 32
#define KF 608                    // 576 quad features (4-aligned rows) + 32 m
#define PSIF_BYTES 311296         // 19456 granules * 16 B (fp16 elements)
#define WS_NEED (PSIF_BYTES + KCOMP * 4)

typedef _Float16 f16x8 __attribute__((ext_vector_type(8)));
typedef __attribute__((ext_vector_type(16))) float f32x16;

// ---- compile-time feature decode: quad-packed triangular, 4-aligned rows ----
constexpr int L4c(int d) { return ((32 - d + 3) / 4) * 4; }
constexpr int PfxC(int d) { int s = 0; for (int i = 0; i < d; ++i) s += L4c(i); return s; }
constexpr int rowOfC(int p) { int d = 0; while (d < 31 && PfxC(d + 1) <= p) ++d; return d; }
constexpr int dOfC(int p) { return (p >= 576) ? -1 : rowOfC(p); }
constexpr int f0OfC(int p) {
    return (p >= 576) ? (p - 576) : ((rowOfC(p) & ~3) + (p - PfxC(rowOfC(p))));
}

__device__ __forceinline__ unsigned short f2h(float v) {
    __half h = __float2half(v);
    return __builtin_bit_cast(unsigned short, h);
}

// ---------------------------------------------------------------------------
// Precompute (unchanged from round 7 — verified)
// ---------------------------------------------------------------------------
__global__ __launch_bounds__(256) void gmm_pre(
    const float* __restrict__ S,
    const float* __restrict__ centers,
    const float* __restrict__ weights,
    unsigned short* __restrict__ PsiF,
    float* __restrict__ kc2)
{
    __shared__ float Sl[DIM][DIM + 1];
    __shared__ float As[DIM][DIM + 1];
    __shared__ float cl[DIM], ml[DIM];
    __shared__ float red[256];

    const int k = blockIdx.x, tid = threadIdx.x;

    for (int idx = tid; idx < DIM * DIM; idx += 256)
        Sl[idx >> 5][idx & 31] = S[(size_t)k * DIM * DIM + idx];
    if (tid < DIM) cl[tid] = centers[k * DIM + tid];
    __syncthreads();

    for (int idx = tid; idx < DIM * DIM; idx += 256) {
        const int d = idx >> 5, f = idx & 31;
        float a = 0.f;
#pragma unroll
        for (int e = 0; e < DIM; ++e) a = fmaf(Sl[d][e], Sl[f][e], a);
        As[d][f] = a;
    }
    __syncthreads();

    if (tid < DIM) {
        float mv = 0.f;
#pragma unroll
        for (int f = 0; f < DIM; ++f) mv = fmaf(As[tid][f], cl[f], mv);
        ml[tid] = mv;
    }
    __syncthreads();

    for (int p = tid; p < KF; p += 256) {
        float val;
        if (p < 576) {
            int d = 0, pr = 0;
            while (true) {
                const int len = ((32 - d + 3) >> 2) << 2;
                if (pr + len > p) break;
                pr += len; ++d;
            }
            const int f = (d & ~3) + (p - pr);
            val = (f < d) ? 0.f : ((f == d) ? -0.5f * As[d][d] : -As[d][f]);
        } else {
            val = ml[p - 576];
        }
        const int c = p >> 6, kk = p & 63;
        const int s = kk >> 4, qq = (kk >> 3) & 1, j = kk & 7;
        const int ct = k >> 5, ll = qq * 32 + (k & 31);
        const int g = c * 2048 + (s * 8 + ct) * 64 + ll;
        PsiF[(size_t)g * 8 + j] = f2h(val);
    }

    red[tid] = fabsf(weights[tid]);
    __syncthreads();
    for (int off = 128; off > 0; off >>= 1) {
        if (tid < off) red[tid] += red[tid + off];
        __syncthreads();
    }
    const float wsum = red[0];

    for (int j = 0; j < DIM - 1; ++j) {
        const float inv = 1.0f / As[j][j];
        for (int idx = tid; idx < DIM * DIM; idx += 256) {
            const int r = idx >> 5, c = idx & 31;
            if (r > j && c > j)
                As[r][c] = fmaf(-As[r][j] * inv, As[j][c], As[r][c]);
        }
        __syncthreads();
    }

    if (tid < DIM) red[tid] = __logf(As[tid][tid]);
    __syncthreads();
    if (tid == 0) {
        float sl = 0.f;
        for (int j = 0; j < DIM; ++j) sl += red[j];
        float cac = 0.f;
        for (int d2 = 0; d2 < DIM; ++d2) cac = fmaf(ml[d2], cl[d2], cac);
        kc2[k] = __logf(fabsf(weights[k])) - __logf(wsum + 1e-30f)
               + 0.5f * sl - 0.5f * cac;
    }
}

// ---------------------------------------------------------------------------
// Main: barrier-free; wave = 128 rows x 64 cols (4 row-tiles x 2 col-tiles);
// b-frags global-loaded with 2-step prefetch distance (bf[3][2]).
// ---------------------------------------------------------------------------
__device__ __forceinline__ unsigned pkmul(unsigned a, unsigned b) {
    __half2 r = __builtin_bit_cast(__half2, a) * __builtin_bit_cast(__half2, b);
    return __builtin_bit_cast(unsigned, r);
}

template<int PA, int PB>
__device__ __forceinline__ void quadProd(const unsigned (&xp)[16], bool hi,
                                         unsigned& o0, unsigned& o1) {
    constexpr int dA = dOfC(PA), fA = f0OfC(PA);
    constexpr int dB = dOfC(PB), fB = f0OfC(PB);
    const unsigned p0 = hi ? xp[(fB >> 1) + 0] : xp[(fA >> 1) + 0];
    const unsigned p1 = hi ? xp[(fB >> 1) + 1] : xp[(fA >> 1) + 1];
    if constexpr (dA < 0) {          // m-features (chunk 9): value = x_f
        o0 = p0; o1 = p1;
    } else {
        const unsigned sA = __builtin_amdgcn_perm(xp[dA >> 1], xp[dA >> 1],
                                (dA & 1) ? 0x03020302u : 0x01000100u);
        const unsigned sB = __builtin_amdgcn_perm(xp[dB >> 1], xp[dB >> 1],
                                (dB & 1) ? 0x03020302u : 0x01000100u);
        const unsigned ss = (dA == dB) ? sA : (hi ? sB : sA);
        o0 = pkmul(ss, p0); o1 = pkmul(ss, p1);
    }
}

template<int C, int S>
__device__ __forceinline__ uint4 genA(const unsigned (&xp)[16], bool hi) {
    constexpr int P = C * 64 + S * 16;
    uint4 u;
    quadProd<P,     P + 8 >(xp, hi, u.x, u.y);   // j 0-3
    quadProd<P + 4, P + 12>(xp, hi, u.z, u.w);   // j 4-7
    return u;
}

template<int ST>   // flat K16-step index 0..37 (chunks 0-8 x4, chunk 9 x2)
__device__ __forceinline__ void doStep(
    const unsigned (&xp)[4][16],
    uint4 (&bf)[3][2], f32x16 (&acc)[4][2],
    const uint4* __restrict__ pb, bool hi)
{
    constexpr int C = (ST < 36) ? ST / 4 : 9;
    constexpr int S = (ST < 36) ? ST % 4 : ST - 36;

    // issue loads for step ST+2 (consumed 2 steps later -> ~2 steps of cover)
    if constexpr (ST + 2 <= 37) {
        constexpr int Cn = (ST + 2 < 36) ? (ST + 2) / 4 : 9;
        constexpr int Sn = (ST + 2 < 36) ? (ST + 2) % 4 : ST + 2 - 36;
#pragma unroll
        for (int ct = 0; ct < 2; ++ct)
            bf[(ST + 2) % 3][ct] = pb[Cn * 2048 + Sn * 512 + ct * 64];
    }

    uint4 a[4];
#pragma unroll
    for (int rt = 0; rt < 4; ++rt) a[rt] = genA<C, S>(xp[rt], hi);

#pragma unroll
    for (int ct = 0; ct < 2; ++ct) {
        const f16x8 b = __builtin_bit_cast(f16x8, bf[ST % 3][ct]);
#pragma unroll
        for (int rt = 0; rt < 4; ++rt)
            acc[rt][ct] = __builtin_amdgcn_mfma_f32_32x32x16_f16(
                __builtin_bit_cast(f16x8, a[rt]), b, acc[rt][ct], 0, 0, 0);
    }
}

template<int ST>
__device__ __forceinline__ void runSteps(
    const unsigned (&xp)[4][16],
    uint4 (&bf)[3][2], f32x16 (&acc)[4][2],
    const uint4* __restrict__ pb, bool hi)
{
    doStep<ST>(xp, bf, acc, pb, hi);
    if constexpr (ST < 37) runSteps<ST + 1>(xp, bf, acc, pb, hi);
}

__global__ __launch_bounds__(256, 2) void gmm_mfma(
    const float* __restrict__ points,
    const unsigned short* __restrict__ PsiF,
    const float* __restrict__ kc2,
    const float* __restrict__ thr,
    float* __restrict__ out)
{
    __shared__ float sPm[128][4], sPs[128][4];   // col-quarter LSE partials

    const int t = threadIdx.x;
    const int w = t >> 6, l = t & 63;            // wave w = col-quarter
    const bool hi = (l >> 5) != 0;

    // x for this lane's 4 row-tiles (rows blk*128 + rt*32 + (l&31)), fp16 pairs
    unsigned xp[4][16];
#pragma unroll
    for (int rt = 0; rt < 4; ++rt) {
        const size_t r = (size_t)blockIdx.x * 128 + rt * 32 + (l & 31);
        const float4* px = (const float4*)(points + r * DIM);
#pragma unroll
        for (int i = 0; i < 8; ++i) {
            float4 v = px[i];
            xp[rt][2*i+0] = __builtin_bit_cast(unsigned, __floats2half2_rn(v.x, v.y));
            xp[rt][2*i+1] = __builtin_bit_cast(unsigned, __floats2half2_rn(v.z, v.w));
        }
    }

    const uint4* pb = (const uint4*)PsiF + w * 128 + l;

    f32x16 acc[4][2];
#pragma unroll
    for (int rt = 0; rt < 4; ++rt)
#pragma unroll
        for (int ct = 0; ct < 2; ++ct)
#pragma unroll
            for (int r = 0; r < 16; ++r) acc[rt][ct][r] = 0.f;

    uint4 bf[3][2];
#pragma unroll
    for (int ct = 0; ct < 2; ++ct) {
        bf[0][ct] = pb[ct * 64];            // step 0 (C=0,S=0)
        bf[1][ct] = pb[512 + ct * 64];      // step 1 (C=0,S=1)
    }

    runSteps<0>(xp, bf, acc, pb, hi);

    // epilogue: LSE over this wave's 64 cols per row, combine quarters via LDS
    float kcv[2];
#pragma unroll
    for (int ct = 0; ct < 2; ++ct) kcv[ct] = kc2[(w * 2 + ct) * 32 + (l & 31)];

#pragma unroll
    for (int rt = 0; rt < 4; ++rt) {
#pragma unroll
        for (int rg = 0; rg < 16; ++rg) {
            const float v0 = acc[rt][0][rg] + kcv[0];
            const float v1 = acc[rt][1][rg] + kcv[1];
            float m = fmaxf(v0, v1);
#pragma unroll
            for (int mask = 1; mask < 32; mask <<= 1)
                m = fmaxf(m, __shfl_xor(m, mask, 64));
            float sv = __expf(v0 - m) + __expf(v1 - m);
#pragma unroll
            for (int mask = 1; mask < 32; mask <<= 1)
                sv += __shfl_xor(sv, mask, 64);
            if ((l & 31) == 0) {
                const int R = rt * 32 + (rg & 3) + 8 * (rg >> 2) + 4 * (l >> 5);
                sPm[R][w] = m; sPs[R][w] = sv;
            }
        }
    }
    __syncthreads();

    if (t < 128) {
        const float m0 = sPm[t][0], m1 = sPm[t][1];
        const float m2 = sPm[t][2], m3 = sPm[t][3];
        const float M = fmaxf(fmaxf(m0, m1), fmaxf(m2, m3));
        const float Sv = sPs[t][0] * __expf(m0 - M) + sPs[t][1] * __expf(m1 - M)
                       + sPs[t][2] * __expf(m2 - M) + sPs[t][3] * __expf(m3 - M);
        out[(size_t)blockIdx.x * 128 + t] = M + __logf(Sv) - thr[0];
    }
}

extern "C" void kernel_launch(void* const* d_in, const int* in_sizes, int n_in,
                              void* d_out, int out_size, void* d_ws, size_t ws_size,
                              hipStream_t stream) {
    const float* points  = (const float*)d_in[0];
    const float* centers = (const float*)d_in[1];
    const float* covs    = (const float*)d_in[2];
    const float* weights = (const float*)d_in[3];
    const float* thr     = (const float*)d_in[4];
    float* out = (float*)d_out;

    unsigned short* PsiF = (unsigned short*)d_ws;
    float* kc2 = (float*)((char*)d_ws + PSIF_BYTES);

    gmm_pre<<<KCOMP, 256, 0, stream>>>(covs, centers, weights, PsiF, kc2);
    gmm_mfma<<<NPTS / 128, 256, 0, stream>>>(points, PsiF, kc2, thr, out);
}

// Round 9
// 152.565 us; speedup vs baseline: 1.2672x; 1.2672x over previous
//
#include <hip/hip_runtime.h>
#include <hip/hip_fp16.h>
#include <math.h>

#define NPTS 131072
#define KCOMP 256
#define DIM 32
#define KF 608                    // 576 quad features (4-aligned rows) + 32 m
#define PSIF_BYTES 311296         // 19456 granules * 16 B (fp16 elements)
#define WS_NEED (PSIF_BYTES + KCOMP * 4)

typedef _Float16 f16x8 __attribute__((ext_vector_type(8)));
typedef __attribute__((ext_vector_type(16))) float f32x16;

// ---- compile-time feature decode: quad-packed triangular, 4-aligned rows ----
constexpr int L4c(int d) { return ((32 - d + 3) / 4) * 4; }
constexpr int PfxC(int d) { int s = 0; for (int i = 0; i < d; ++i) s += L4c(i); return s; }
constexpr int rowOfC(int p) { int d = 0; while (d < 31 && PfxC(d + 1) <= p) ++d; return d; }
constexpr int dOfC(int p) { return (p >= 576) ? -1 : rowOfC(p); }
constexpr int f0OfC(int p) {
    return (p >= 576) ? (p - 576) : ((rowOfC(p) & ~3) + (p - PfxC(rowOfC(p))));
}

__device__ __forceinline__ unsigned short f2h(float v) {
    __half h = __float2half(v);
    return __builtin_bit_cast(unsigned short, h);
}

// LDS-only barrier: drain lgkmcnt but leave global loads (vmcnt) in flight.
__device__ __forceinline__ void barrier_lds_only() {
    asm volatile("s_waitcnt lgkmcnt(0)\ns_barrier" ::: "memory");
}

// ---------------------------------------------------------------------------
// Precompute (unchanged from rounds 7/8 — verified; Psi fp16, frag-ordered)
// ---------------------------------------------------------------------------
__global__ __launch_bounds__(256) void gmm_pre(
    const float* __restrict__ S,
    const float* __restrict__ centers,
    const float* __restrict__ weights,
    unsigned short* __restrict__ PsiF,
    float* __restrict__ kc2)
{
    __shared__ float Sl[DIM][DIM + 1];
    __shared__ float As[DIM][DIM + 1];
    __shared__ float cl[DIM], ml[DIM];
    __shared__ float red[256];

    const int k = blockIdx.x, tid = threadIdx.x;

    for (int idx = tid; idx < DIM * DIM; idx += 256)
        Sl[idx >> 5][idx & 31] = S[(size_t)k * DIM * DIM + idx];
    if (tid < DIM) cl[tid] = centers[k * DIM + tid];
    __syncthreads();

    for (int idx = tid; idx < DIM * DIM; idx += 256) {
        const int d = idx >> 5, f = idx & 31;
        float a = 0.f;
#pragma unroll
        for (int e = 0; e < DIM; ++e) a = fmaf(Sl[d][e], Sl[f][e], a);
        As[d][f] = a;
    }
    __syncthreads();

    if (tid < DIM) {
        float mv = 0.f;
#pragma unroll
        for (int f = 0; f < DIM; ++f) mv = fmaf(As[tid][f], cl[f], mv);
        ml[tid] = mv;
    }
    __syncthreads();

    for (int p = tid; p < KF; p += 256) {
        float val;
        if (p < 576) {
            int d = 0, pr = 0;
            while (true) {
                const int len = ((32 - d + 3) >> 2) << 2;
                if (pr + len > p) break;
                pr += len; ++d;
            }
            const int f = (d & ~3) + (p - pr);
            val = (f < d) ? 0.f : ((f == d) ? -0.5f * As[d][d] : -As[d][f]);
        } else {
            val = ml[p - 576];
        }
        const int c = p >> 6, kk = p & 63;
        const int s = kk >> 4, qq = (kk >> 3) & 1, j = kk & 7;
        const int ct = k >> 5, ll = qq * 32 + (k & 31);
        const int g = c * 2048 + (s * 8 + ct) * 64 + ll;
        PsiF[(size_t)g * 8 + j] = f2h(val);
    }

    red[tid] = fabsf(weights[tid]);
    __syncthreads();
    for (int off = 128; off > 0; off >>= 1) {
        if (tid < off) red[tid] += red[tid + off];
        __syncthreads();
    }
    const float wsum = red[0];

    for (int j = 0; j < DIM - 1; ++j) {
        const float inv = 1.0f / As[j][j];
        for (int idx = tid; idx < DIM * DIM; idx += 256) {
            const int r = idx >> 5, c = idx & 31;
            if (r > j && c > j)
                As[r][c] = fmaf(-As[r][j] * inv, As[j][c], As[r][c]);
        }
        __syncthreads();
    }

    if (tid < DIM) red[tid] = __logf(As[tid][tid]);
    __syncthreads();
    if (tid == 0) {
        float sl = 0.f;
        for (int j = 0; j < DIM; ++j) sl += red[j];
        float cac = 0.f;
        for (int d2 = 0; d2 < DIM; ++d2) cac = fmaf(ml[d2], cl[d2], cac);
        kc2[k] = __logf(fabsf(weights[k])) - __logf(wsum + 1e-30f)
               + 0.5f * sl - 0.5f * cac;
    }
}

// ---------------------------------------------------------------------------
// Main: block = 64 rows x 256 cols, 4 waves of 64x64 (acc 64 AGPR).
// A genned cooperatively into double-buffered LDS (1 lgkm-only barrier/chunk);
// B register-prefetched from global, distance 3. 3 waves/SIMD target.
// ---------------------------------------------------------------------------
__device__ __forceinline__ unsigned pkmul(unsigned a, unsigned b) {
    __half2 r = __builtin_bit_cast(__half2, a) * __builtin_bit_cast(__half2, b);
    return __builtin_bit_cast(unsigned, r);
}

template<int P>
__device__ __forceinline__ void genQuadH(const unsigned (&xp)[16],
                                         unsigned& o0, unsigned& o1) {
    constexpr int d = dOfC(P);
    constexpr int f0 = f0OfC(P);       // 4-aligned -> f0>>1 is even
    const unsigned p0 = xp[(f0 >> 1) + 0];
    const unsigned p1 = xp[(f0 >> 1) + 1];
    if constexpr (d < 0) { o0 = p0; o1 = p1; }   // m-features: value = x_f
    else {
        const unsigned ss = __builtin_amdgcn_perm(xp[d >> 1], xp[d >> 1],
                                (d & 1) ? 0x03020302u : 0x01000100u);
        o0 = pkmul(ss, p0); o1 = pkmul(ss, p1);
    }
}

// site (C,SS) of this thread's row: features C*64+SS*8 .. +7, h = SS&1
template<int C, int SS>
__device__ __forceinline__ void genSiteH(const unsigned (&xp)[16],
                                         uint4* buf, int row) {
    uint4 u;
    genQuadH<C * 64 + SS * 8>(xp, u.x, u.y);
    genQuadH<C * 64 + SS * 8 + 4>(xp, u.z, u.w);
    buf[(SS >> 1) * 128 + (row >> 5) * 64 + (SS & 1) * 32 + (row & 31)] = u;
}

template<int ST>
__device__ __forceinline__ void doStep(
    const uint4* buf, uint4 (&bf)[4][2], f32x16 (&acc)[2][2],
    const uint4* __restrict__ pb, int l)
{
    constexpr int S = (ST < 36) ? ST % 4 : ST - 36;   // step within chunk

    // issue b-loads for step ST+3 (distance-3 cover; SSA regs -> precise vmcnt)
    if constexpr (ST + 3 <= 37) {
#pragma unroll
        for (int ct = 0; ct < 2; ++ct)
            bf[(ST + 3) & 3][ct] = pb[(ST + 3) * 512 + ct * 64];
    }

    const f16x8 a0 = __builtin_bit_cast(f16x8, buf[S * 128 + 0 * 64 + l]);
    const f16x8 a1 = __builtin_bit_cast(f16x8, buf[S * 128 + 1 * 64 + l]);
#pragma unroll
    for (int ct = 0; ct < 2; ++ct) {
        const f16x8 b = __builtin_bit_cast(f16x8, bf[ST & 3][ct]);
        acc[0][ct] = __builtin_amdgcn_mfma_f32_32x32x16_f16(a0, b, acc[0][ct], 0, 0, 0);
        acc[1][ct] = __builtin_amdgcn_mfma_f32_32x32x16_f16(a1, b, acc[1][ct], 0, 0, 0);
    }
}

template<int C>
__device__ __forceinline__ void doChunk(
    const unsigned (&xp)[16], uint4* sA4,
    uint4 (&bf)[4][2], f32x16 (&acc)[2][2],
    const uint4* __restrict__ pb, int l, int sub, int row)
{
    constexpr int NS = (C < 9) ? 4 : 2;
    uint4* buf = sA4 + (C & 1) * 512;

    // cooperative gen: 4 thread-groups (sub = wave id, uniform) x 1-2 sites
    if constexpr (NS == 4) {
        switch (sub) {
        case 0: genSiteH<C, 0>(xp, buf, row); genSiteH<C, 4>(xp, buf, row); break;
        case 1: genSiteH<C, 1>(xp, buf, row); genSiteH<C, 5>(xp, buf, row); break;
        case 2: genSiteH<C, 2>(xp, buf, row); genSiteH<C, 6>(xp, buf, row); break;
        default: genSiteH<C, 3>(xp, buf, row); genSiteH<C, 7>(xp, buf, row); break;
        }
    } else {
        switch (sub) {
        case 0: genSiteH<C, 0>(xp, buf, row); break;
        case 1: genSiteH<C, 1>(xp, buf, row); break;
        case 2: genSiteH<C, 2>(xp, buf, row); break;
        default: genSiteH<C, 3>(xp, buf, row); break;
        }
    }
    barrier_lds_only();   // lgkm drain only; b-loads stay in flight

    doStep<C * 4 + 0>(buf, bf, acc, pb, l);
    doStep<C * 4 + 1>(buf, bf, acc, pb, l);
    if constexpr (NS == 4) {
        doStep<C * 4 + 2>(buf, bf, acc, pb, l);
        doStep<C * 4 + 3>(buf, bf, acc, pb, l);
    }
}

__global__ __launch_bounds__(256, 3) void gmm_mfma(
    const float* __restrict__ points,
    const unsigned short* __restrict__ PsiF,
    const float* __restrict__ kc2,
    const float* __restrict__ thr,
    float* __restrict__ out)
{
    __shared__ uint4 sA4[1024];            // 16 KB: A double buffer (2x8 KB)
    __shared__ float sPm[64][4], sPs[64][4];

    const int t = threadIdx.x;
    const int cq = t >> 6, l = t & 63;     // wave = col quarter (64 cols)
    const int row = l;                     // gen: thread owns row l, group cq

    // b pointer: granule = ST*512 + (cq*2+ct)*64 + l
    const uint4* pb = (const uint4*)PsiF + cq * 128 + l;

    // load this row's x, pack fp32 -> fp16 pairs (16 VGPRs)
    unsigned xp[16];
    {
        const float4* px = (const float4*)(points + ((size_t)blockIdx.x * 64 + row) * DIM);
#pragma unroll
        for (int i = 0; i < 8; ++i) {
            float4 v = px[i];
            xp[2 * i + 0] = __builtin_bit_cast(unsigned, __floats2half2_rn(v.x, v.y));
            xp[2 * i + 1] = __builtin_bit_cast(unsigned, __floats2half2_rn(v.z, v.w));
        }
    }

    uint4 bf[4][2];
#pragma unroll
    for (int st = 0; st < 3; ++st)         // prologue: steps 0..2 in flight
#pragma unroll
        for (int ct = 0; ct < 2; ++ct)
            bf[st][ct] = pb[st * 512 + ct * 64];

    f32x16 acc[2][2];
#pragma unroll
    for (int a = 0; a < 2; ++a)
#pragma unroll
        for (int c = 0; c < 2; ++c)
#pragma unroll
            for (int r = 0; r < 16; ++r) acc[a][c][r] = 0.f;

    doChunk<0>(xp, sA4, bf, acc, pb, l, cq, row);
    doChunk<1>(xp, sA4, bf, acc, pb, l, cq, row);
    doChunk<2>(xp, sA4, bf, acc, pb, l, cq, row);
    doChunk<3>(xp, sA4, bf, acc, pb, l, cq, row);
    doChunk<4>(xp, sA4, bf, acc, pb, l, cq, row);
    doChunk<5>(xp, sA4, bf, acc, pb, l, cq, row);
    doChunk<6>(xp, sA4, bf, acc, pb, l, cq, row);
    doChunk<7>(xp, sA4, bf, acc, pb, l, cq, row);
    doChunk<8>(xp, sA4, bf, acc, pb, l, cq, row);
    doChunk<9>(xp, sA4, bf, acc, pb, l, cq, row);

    // epilogue: LSE over this wave's 64 cols per row, combine quarters via LDS
    float kcv[2];
#pragma unroll
    for (int ct = 0; ct < 2; ++ct) kcv[ct] = kc2[(cq * 2 + ct) * 32 + (l & 31)];

#pragma unroll
    for (int rt = 0; rt < 2; ++rt) {
#pragma unroll
        for (int rg = 0; rg < 16; ++rg) {
            const float v0 = acc[rt][0][rg] + kcv[0];
            const float v1 = acc[rt][1][rg] + kcv[1];
            float m = fmaxf(v0, v1);
#pragma unroll
            for (int mask = 1; mask < 32; mask <<= 1)
                m = fmaxf(m, __shfl_xor(m, mask, 64));
            float sv = __expf(v0 - m) + __expf(v1 - m);
#pragma unroll
            for (int mask = 1; mask < 32; mask <<= 1)
                sv += __shfl_xor(sv, mask, 64);
            if ((l & 31) == 0) {
                const int R = rt * 32 + (rg & 3) + 8 * (rg >> 2) + 4 * (l >> 5);
                sPm[R][cq] = m; sPs[R][cq] = sv;
            }
        }
    }
    __syncthreads();

    if (t < 64) {
        const float m0 = sPm[t][0], m1 = sPm[t][1];
        const float m2 = sPm[t][2], m3 = sPm[t][3];
        const float M = fmaxf(fmaxf(m0, m1), fmaxf(m2, m3));
        const float Sv = sPs[t][0] * __expf(m0 - M) + sPs[t][1] * __expf(m1 - M)
                       + sPs[t][2] * __expf(m2 - M) + sPs[t][3] * __expf(m3 - M);
        out[(size_t)blockIdx.x * 64 + t] = M + __logf(Sv) - thr[0];
    }
}

extern "C" void kernel_launch(void* const* d_in, const int* in_sizes, int n_in,
                              void* d_out, int out_size, void* d_ws, size_t ws_size,
                              hipStream_t stream) {
    const float* points  = (const float*)d_in[0];
    const float* centers = (const float*)d_in[1];
    const float* covs    = (const float*)d_in[2];
    const float* weights = (const float*)d_in[3];
    const float* thr     = (const float*)d_in[4];
    float* out = (float*)d_out;

    unsigned short* PsiF = (unsigned short*)d_ws;
    float* kc2 = (float*)((char*)d_ws + PSIF_BYTES);

    gmm_pre<<<KCOMP, 256, 0, stream>>>(covs, centers, weights, PsiF, kc2);
    gmm_mfma<<<NPTS / 64, 256, 0, stream>>>(points, PsiF, kc2, thr, out);
}